// Round 5
// baseline (82.723 us; speedup 1.0000x reference)
//
#include <hip/hip_runtime.h>
#include <hip/hip_bf16.h>

#define N 8192
#define D 192
#define BROWS 256                    // rows per block = 4 waves x 64
#define BCOLS 128                    // cols per block
#define NCCHUNK (N / BCOLS)          // 64 col-chunks
#define FRAG_BYTES 1024              // one MFMA B fragment: 64 lanes x 16B
#define NFRAGS ((BCOLS / 16) * 6)    // 48 fragments = 48 KB B panel

typedef short short8 __attribute__((ext_vector_type(8)));
typedef int int4v __attribute__((ext_vector_type(4)));
typedef float f32x4 __attribute__((ext_vector_type(4)));

#define GLOAD16(gptr, lptr)                                                               \
  __builtin_amdgcn_global_load_lds((const __attribute__((address_space(1))) void*)(gptr), \
                                   (__attribute__((address_space(3))) void*)(lptr), 16, 0, 0)

// ---------------- Kernel 1: row-normalize + diagonal dot (fp32) ----------------
// posn pre-scaled by w*log2e so the GEMM accumulator directly holds the exp2
// argument (c0 offset seeds the accumulator).
__global__ __launch_bounds__(256) void norm_kernel(
    const float* __restrict__ x,
    const float* __restrict__ wp,
    __hip_bfloat16* __restrict__ posn,
    __hip_bfloat16* __restrict__ ancn,
    float* __restrict__ diag) {
  const float c1 = (*wp) * 1.4426950408889634f;
  int gw = (int)((blockIdx.x * 256 + threadIdx.x) >> 6);
  int lane = threadIdx.x & 63;
  if (gw >= N) return;
  const float* row = x + (size_t)gw * (2 * D);
  float p[3], a[3];
  float ssp = 0.f, ssa = 0.f, dt = 0.f;
#pragma unroll
  for (int j = 0; j < 3; ++j) {
    p[j] = row[lane + 64 * j];
    a[j] = row[D + lane + 64 * j];
    ssp += p[j] * p[j];
    ssa += a[j] * a[j];
    dt += p[j] * a[j];
  }
#pragma unroll
  for (int off = 32; off >= 1; off >>= 1) {
    ssp += __shfl_xor(ssp, off, 64);
    ssa += __shfl_xor(ssa, off, 64);
    dt += __shfl_xor(dt, off, 64);
  }
  float invp = 1.f / fmaxf(sqrtf(ssp), 1e-8f);
  float inva = 1.f / fmaxf(sqrtf(ssa), 1e-8f);
#pragma unroll
  for (int j = 0; j < 3; ++j) {
    posn[(size_t)gw * D + lane + 64 * j] = __float2bfloat16(p[j] * invp * c1);
    ancn[(size_t)gw * D + lane + 64 * j] = __float2bfloat16(a[j] * inva);
  }
  if (lane == 0) diag[gw] = dt * invp * inva;
}

// ---------------- Kernel 2: one-shot-staged GEMM + fused partial sum-exp -------
// Block = 4 waves x 64 rows = 256 rows x 128 cols. Full B panel (48 KB) staged
// once via global_load_lds in MFMA-fragment order; ONE __syncthreads, then a
// barrier-free MFMA/exp2 stream. A fragments are PINNED in VGPRs via an asm
// opacity barrier -- Round 4's compiler (VGPR_Count=88 < the 96 af needs)
// rematerialized the af global loads inside the ct-loop, turning the hot loop
// L2-latency-bound (MfmaUtil 22%). The "+v" asm redefines the values, making
// rematerialization impossible. acc seeded with c0 = -|w|*log2e => exp2(acc).
__global__ __launch_bounds__(256) __attribute__((amdgpu_waves_per_eu(2)))
void gemm_lse_kernel(
    const __hip_bfloat16* __restrict__ posn,
    const __hip_bfloat16* __restrict__ ancn,
    const float* __restrict__ wp,
    float* __restrict__ partial) {
  __shared__ char lds[NFRAGS * FRAG_BYTES];  // 48 KB, single buffer

  const int lane = (int)(threadIdx.x & 63);
  const int wv = (int)(threadIdx.x >> 6);
  const int cchunk = (int)(blockIdx.x & (NCCHUNK - 1));
  const int rb = (int)(blockIdx.x >> 6);
  const int rowBase = rb * BROWS + wv * 64;
  const int colBase = cchunk * BCOLS;

  const float c0 = -fabsf(*wp) * 1.4426950408889634f;  // (b - M)*log2e, M = |w|+b

  const int r15 = lane & 15;
  const int khi = (lane >> 4) * 8;

  // Stage whole B panel: wave wv stages coltiles 2wv and 2wv+1 (12 frags each).
#pragma unroll
  for (int j = 0; j < 12; ++j) {
    const int ct = wv * 2 + (j / 6);
    const int ks = j % 6;
    const __hip_bfloat16* g = ancn + (size_t)(colBase + ct * 16 + r15) * D + ks * 32 + khi;
    GLOAD16(g, lds + (ct * 6 + ks) * FRAG_BYTES);
  }

  // A fragments: 4 rowsets x 6 ksteps, 16B/lane = 96 VGPRs, pinned live.
  int4v af[4][6];
#pragma unroll
  for (int rs = 0; rs < 4; ++rs)
#pragma unroll
    for (int ks = 0; ks < 6; ++ks) {
      af[rs][ks] = *(const int4v*)(posn + (size_t)(rowBase + rs * 16 + r15) * D + ks * 32 + khi);
      asm volatile("" : "+v"(af[rs][ks]));  // opaque: no remat, stays in VGPRs
    }

  float s[4][4];
#pragma unroll
  for (int rs = 0; rs < 4; ++rs)
#pragma unroll
    for (int r = 0; r < 4; ++r) s[rs][r] = 0.f;

  __syncthreads();  // the ONLY barrier: B panel resident from here on

#pragma unroll 2
  for (int ct = 0; ct < BCOLS / 16; ++ct) {
    f32x4 acc[4];
#pragma unroll
    for (int rs = 0; rs < 4; ++rs) acc[rs] = (f32x4){c0, c0, c0, c0};
#pragma unroll
    for (int ks = 0; ks < 6; ++ks) {
      short8 bfk = *(const short8*)(lds + (ct * 6 + ks) * FRAG_BYTES + lane * 16);
#pragma unroll
      for (int rs = 0; rs < 4; ++rs)
        acc[rs] = __builtin_amdgcn_mfma_f32_16x16x32_bf16(
            __builtin_bit_cast(short8, af[rs][ks]), bfk, acc[rs], 0, 0, 0);
    }
#pragma unroll
    for (int rs = 0; rs < 4; ++rs)
#pragma unroll
      for (int r = 0; r < 4; ++r)
        s[rs][r] += __builtin_amdgcn_exp2f(acc[rs][r]);
  }

  // Reduce across the 16 lanes holding the 16 cols of each C tile
#pragma unroll
  for (int off = 1; off < 16; off <<= 1)
#pragma unroll
    for (int rs = 0; rs < 4; ++rs)
#pragma unroll
      for (int r = 0; r < 4; ++r) s[rs][r] += __shfl_xor(s[rs][r], off, 64);

  if (r15 == 0) {
    const int rgrp = (lane >> 4) * 4;  // C rows: (lane>>4)*4 + reg
#pragma unroll
    for (int rs = 0; rs < 4; ++rs)
#pragma unroll
      for (int r = 0; r < 4; ++r)
        partial[(size_t)cchunk * N + rowBase + rs * 16 + rgrp + r] = s[rs][r];
  }
}

// ---------------- Kernel 3a: per-row LSE + per-block partial mean ----------------
__global__ __launch_bounds__(256) void finalize1_kernel(
    const float* __restrict__ partial,
    const float* __restrict__ diag,
    const float* __restrict__ wp,
    const float* __restrict__ bp,
    float* __restrict__ blocksum) {
  const float w = *wp, b = *bp;
  const float M = fabsf(w) + b;
  int i = (int)(blockIdx.x * 256 + threadIdx.x);
  float s = 0.f;
#pragma unroll
  for (int c = 0; c < NCCHUNK; ++c) s += partial[(size_t)c * N + i];
  float acc = fmaf(diag[i], w, b) - (M + logf(s));
#pragma unroll
  for (int off = 32; off >= 1; off >>= 1) acc += __shfl_xor(acc, off, 64);
  __shared__ float red[4];
  if ((threadIdx.x & 63) == 0) red[threadIdx.x >> 6] = acc;
  __syncthreads();
  if (threadIdx.x == 0) blocksum[blockIdx.x] = red[0] + red[1] + red[2] + red[3];
}

// ---------------- Kernel 3b: combine 32 block sums -> loss ----------------
__global__ __launch_bounds__(64) void finalize2_kernel(
    const float* __restrict__ blocksum, float* __restrict__ out) {
  int lane = (int)threadIdx.x;
  float v = (lane < 32) ? blocksum[lane] : 0.f;
#pragma unroll
  for (int off = 32; off >= 1; off >>= 1) v += __shfl_xor(v, off, 64);
  if (lane == 0) out[0] = -v / (float)N;
}

extern "C" void kernel_launch(void* const* d_in, const int* in_sizes, int n_in,
                              void* d_out, int out_size, void* d_ws, size_t ws_size,
                              hipStream_t stream) {
  const float* x = (const float*)d_in[0];
  const float* wp = (const float*)d_in[1];
  const float* bp = (const float*)d_in[2];
  float* out = (float*)d_out;

  char* ws = (char*)d_ws;
  __hip_bfloat16* posn = (__hip_bfloat16*)ws;                 // 3,145,728 B
  __hip_bfloat16* ancn = (__hip_bfloat16*)(ws + 3145728);     // 3,145,728 B
  float* diag = (float*)(ws + 6291456);                       // 32,768 B
  float* partial = (float*)(ws + 6324224);                    // 64*8192*4 = 2,097,152 B
  float* blocksum = (float*)(ws + 8421376);                   // 128 B

  norm_kernel<<<N / 4, 256, 0, stream>>>(x, wp, posn, ancn, diag);
  gemm_lse_kernel<<<(N / BROWS) * NCCHUNK, 256, 0, stream>>>(posn, ancn, wp, partial);
  finalize1_kernel<<<N / 256, 256, 0, stream>>>(partial, diag, wp, bp, blocksum);
  finalize2_kernel<<<1, 64, 0, stream>>>(blocksum, out);
}

// Round 6
// 70.781 us; speedup vs baseline: 1.1687x; 1.1687x over previous
//
#include <hip/hip_runtime.h>
#include <hip/hip_bf16.h>

#define N 8192
#define D 192
#define BROWS 256                    // rows per block = 4 waves x 64
#define BCOLS 128                    // cols per block
#define NCCHUNK (N / BCOLS)          // 64 col-chunks
#define FRAG_BYTES 1024              // one MFMA B fragment: 64 lanes x 16B
#define NFRAGS ((BCOLS / 16) * 6)    // 48 fragments = 48 KB B panel

typedef short short8 __attribute__((ext_vector_type(8)));
typedef float f32x4 __attribute__((ext_vector_type(4)));

#define GLOAD16(gptr, lptr)                                                               \
  __builtin_amdgcn_global_load_lds((const __attribute__((address_space(1))) void*)(gptr), \
                                   (__attribute__((address_space(3))) void*)(lptr), 16, 0, 0)

// ---------------- Kernel 1: row-normalize + diagonal dot (fp32) ----------------
// posn pre-scaled by w*log2e so the GEMM accumulator directly holds the exp2
// argument (c0 offset seeds the accumulator).
__global__ __launch_bounds__(256) void norm_kernel(
    const float* __restrict__ x,
    const float* __restrict__ wp,
    __hip_bfloat16* __restrict__ posn,
    __hip_bfloat16* __restrict__ ancn,
    float* __restrict__ diag) {
  const float c1 = (*wp) * 1.4426950408889634f;
  int gw = (int)((blockIdx.x * 256 + threadIdx.x) >> 6);
  int lane = threadIdx.x & 63;
  if (gw >= N) return;
  const float* row = x + (size_t)gw * (2 * D);
  float p[3], a[3];
  float ssp = 0.f, ssa = 0.f, dt = 0.f;
#pragma unroll
  for (int j = 0; j < 3; ++j) {
    p[j] = row[lane + 64 * j];
    a[j] = row[D + lane + 64 * j];
    ssp += p[j] * p[j];
    ssa += a[j] * a[j];
    dt += p[j] * a[j];
  }
#pragma unroll
  for (int off = 32; off >= 1; off >>= 1) {
    ssp += __shfl_xor(ssp, off, 64);
    ssa += __shfl_xor(ssa, off, 64);
    dt += __shfl_xor(dt, off, 64);
  }
  float invp = 1.f / fmaxf(sqrtf(ssp), 1e-8f);
  float inva = 1.f / fmaxf(sqrtf(ssa), 1e-8f);
#pragma unroll
  for (int j = 0; j < 3; ++j) {
    posn[(size_t)gw * D + lane + 64 * j] = __float2bfloat16(p[j] * invp * c1);
    ancn[(size_t)gw * D + lane + 64 * j] = __float2bfloat16(a[j] * inva);
  }
  if (lane == 0) diag[gw] = dt * invp * inva;
}

// ---------------- Kernel 2: one-shot-staged GEMM + fused partial sum-exp -------
// Block = 4 waves x 64 rows = 256 rows x 128 cols. Full B panel (48 KB) staged
// once via global_load_lds in MFMA-fragment order; ONE __syncthreads, then a
// barrier-free MFMA/exp2 stream.
//
// Register story (R2-R5 post-mortems): af[4][6] = 96 VGPR must be RESIDENT.
// Total need ~155. waves_per_eu(3,3) pins the budget at 512/3 = 170 regs on
// BOTH ends: cap 170 > 155 (no spill/remat, unlike R2's 128-cap and R4's
// 88-heuristic) and min 3 (no occupancy-chasing shrink, unlike R5's 76).
// 48 KB LDS -> exactly 3 blocks/CU = 12 waves/CU.
__global__ __launch_bounds__(256) __attribute__((amdgpu_waves_per_eu(3, 3)))
void gemm_lse_kernel(
    const __hip_bfloat16* __restrict__ posn,
    const __hip_bfloat16* __restrict__ ancn,
    const float* __restrict__ wp,
    float* __restrict__ partial) {
  __shared__ char lds[NFRAGS * FRAG_BYTES];  // 48 KB, single buffer

  const int lane = (int)(threadIdx.x & 63);
  const int wv = (int)(threadIdx.x >> 6);
  const int cchunk = (int)(blockIdx.x & (NCCHUNK - 1));
  const int rb = (int)(blockIdx.x >> 6);
  const int rowBase = rb * BROWS + wv * 64;
  const int colBase = cchunk * BCOLS;

  const float c0 = -fabsf(*wp) * 1.4426950408889634f;  // (b - M)*log2e, M = |w|+b

  const int r15 = lane & 15;
  const int khi = (lane >> 4) * 8;

  // Stage whole B panel: wave wv stages coltiles 2wv and 2wv+1 (12 frags each).
#pragma unroll
  for (int j = 0; j < 12; ++j) {
    const int ct = wv * 2 + (j / 6);
    const int ks = j % 6;
    const __hip_bfloat16* g = ancn + (size_t)(colBase + ct * 16 + r15) * D + ks * 32 + khi;
    GLOAD16(g, lds + (ct * 6 + ks) * FRAG_BYTES);
  }

  // A fragments: 4 rowsets x 6 ksteps, 16B/lane = 96 VGPRs, live whole kernel.
  short8 af[4][6];
#pragma unroll
  for (int rs = 0; rs < 4; ++rs)
#pragma unroll
    for (int ks = 0; ks < 6; ++ks)
      af[rs][ks] = *(const short8*)(posn + (size_t)(rowBase + rs * 16 + r15) * D + ks * 32 + khi);

  float s[4][4];
#pragma unroll
  for (int rs = 0; rs < 4; ++rs)
#pragma unroll
    for (int r = 0; r < 4; ++r) s[rs][r] = 0.f;

  __syncthreads();  // the ONLY barrier: B panel resident from here on

#pragma unroll 2
  for (int ct = 0; ct < BCOLS / 16; ++ct) {
    f32x4 acc[4];
#pragma unroll
    for (int rs = 0; rs < 4; ++rs) acc[rs] = (f32x4){c0, c0, c0, c0};
#pragma unroll
    for (int ks = 0; ks < 6; ++ks) {
      short8 bfk = *(const short8*)(lds + (ct * 6 + ks) * FRAG_BYTES + lane * 16);
#pragma unroll
      for (int rs = 0; rs < 4; ++rs)
        acc[rs] = __builtin_amdgcn_mfma_f32_16x16x32_bf16(af[rs][ks], bfk, acc[rs], 0, 0, 0);
    }
#pragma unroll
    for (int rs = 0; rs < 4; ++rs)
#pragma unroll
      for (int r = 0; r < 4; ++r)
        s[rs][r] += __builtin_amdgcn_exp2f(acc[rs][r]);
  }

  // Reduce across the 16 lanes holding the 16 cols of each C tile
#pragma unroll
  for (int off = 1; off < 16; off <<= 1)
#pragma unroll
    for (int rs = 0; rs < 4; ++rs)
#pragma unroll
      for (int r = 0; r < 4; ++r) s[rs][r] += __shfl_xor(s[rs][r], off, 64);

  if (r15 == 0) {
    const int rgrp = (lane >> 4) * 4;  // C rows: (lane>>4)*4 + reg
#pragma unroll
    for (int rs = 0; rs < 4; ++rs)
#pragma unroll
      for (int r = 0; r < 4; ++r)
        partial[(size_t)cchunk * N + rowBase + rs * 16 + rgrp + r] = s[rs][r];
  }
}

// ---------------- Kernel 3a: per-row LSE + per-block partial mean ----------------
__global__ __launch_bounds__(256) void finalize1_kernel(
    const float* __restrict__ partial,
    const float* __restrict__ diag,
    const float* __restrict__ wp,
    const float* __restrict__ bp,
    float* __restrict__ blocksum) {
  const float w = *wp, b = *bp;
  const float M = fabsf(w) + b;
  int i = (int)(blockIdx.x * 256 + threadIdx.x);
  float s = 0.f;
#pragma unroll
  for (int c = 0; c < NCCHUNK; ++c) s += partial[(size_t)c * N + i];
  float acc = fmaf(diag[i], w, b) - (M + logf(s));
#pragma unroll
  for (int off = 32; off >= 1; off >>= 1) acc += __shfl_xor(acc, off, 64);
  __shared__ float red[4];
  if ((threadIdx.x & 63) == 0) red[threadIdx.x >> 6] = acc;
  __syncthreads();
  if (threadIdx.x == 0) blocksum[blockIdx.x] = red[0] + red[1] + red[2] + red[3];
}

// ---------------- Kernel 3b: combine 32 block sums -> loss ----------------
__global__ __launch_bounds__(64) void finalize2_kernel(
    const float* __restrict__ blocksum, float* __restrict__ out) {
  int lane = (int)threadIdx.x;
  float v = (lane < 32) ? blocksum[lane] : 0.f;
#pragma unroll
  for (int off = 32; off >= 1; off >>= 1) v += __shfl_xor(v, off, 64);
  if (lane == 0) out[0] = -v / (float)N;
}

extern "C" void kernel_launch(void* const* d_in, const int* in_sizes, int n_in,
                              void* d_out, int out_size, void* d_ws, size_t ws_size,
                              hipStream_t stream) {
  const float* x = (const float*)d_in[0];
  const float* wp = (const float*)d_in[1];
  const float* bp = (const float*)d_in[2];
  float* out = (float*)d_out;

  char* ws = (char*)d_ws;
  __hip_bfloat16* posn = (__hip_bfloat16*)ws;                 // 3,145,728 B
  __hip_bfloat16* ancn = (__hip_bfloat16*)(ws + 3145728);     // 3,145,728 B
  float* diag = (float*)(ws + 6291456);                       // 32,768 B
  float* partial = (float*)(ws + 6324224);                    // 64*8192*4 = 2,097,152 B
  float* blocksum = (float*)(ws + 8421376);                   // 128 B

  norm_kernel<<<N / 4, 256, 0, stream>>>(x, wp, posn, ancn, diag);
  gemm_lse_kernel<<<(N / BROWS) * NCCHUNK, 256, 0, stream>>>(posn, ancn, wp, partial);
  finalize1_kernel<<<N / 256, 256, 0, stream>>>(partial, diag, wp, bp, blocksum);
  finalize2_kernel<<<1, 64, 0, stream>>>(blocksum, out);
}